// Round 1
// baseline (2503.903 us; speedup 1.0000x reference)
//
#include <hip/hip_runtime.h>
#include <math.h>

#define BB 4
#define CC 64
#define HH 64
#define WW 64

// workspace layout (float offsets)
#define OFF_H1     0                              // 4*256*64*64 = 4194304
#define OFF_H      (4*256*64*64)                  // 4*64*64*64  = 1048576
#define OFF_T      (OFF_H + 4*64*64*64)           // 4*64*64     = 16384
#define OFF_POOLED (OFF_T + 4*64*64)              // 256
#define OFF_DW     (OFF_POOLED + 256)             // 4*576 = 2304
#define OFF_XD     (OFF_DW + 4*576)               // 4*4*64*64 = 65536
#define OFF_STATS  (OFF_XD + 4*4*64*64)           // 128

// ---------------- conv1: C=64 -> 256, 3x3 pad1, + bias + relu ----------------
__global__ __launch_bounds__(256) void conv1_relu(
    const float* __restrict__ x, const float* __restrict__ w1,
    const float* __restrict__ b1, float* __restrict__ h1) {
  int bid = blockIdx.x;
  int y   = bid & 63;
  int ocb = (bid >> 6) & 3;
  int b   = bid >> 8;
  __shared__ float lds[3 * 64 * 66];  // [dy][ic][x+1], zero-padded cols
  int tid = threadIdx.x;
  for (int idx = tid; idx < 3 * 64 * 66; idx += 256) {
    int dy  = idx / (64 * 66);
    int rem = idx - dy * (64 * 66);
    int ic  = rem / 66;
    int xx  = rem - ic * 66;
    int yy  = y + dy - 1;
    int xi  = xx - 1;
    float v = 0.f;
    if (yy >= 0 && yy < 64 && xi >= 0 && xi < 64)
      v = x[((b * 64 + ic) * 64 + yy) * 64 + xi];
    lds[idx] = v;
  }
  __syncthreads();
  int xq = tid & 15, og = tid >> 4;
  int x4 = xq * 4;
  int oc0 = ocb * 64 + og * 4;
  float acc[4][4] = {};
  const float* w1p = w1 + oc0 * 64 * 9;
  for (int ic = 0; ic < 64; ++ic) {
#pragma unroll
    for (int ky = 0; ky < 3; ++ky) {
      const float* lrow = &lds[(ky * 64 + ic) * 66 + x4];
      float v[6];
#pragma unroll
      for (int q = 0; q < 6; ++q) v[q] = lrow[q];
#pragma unroll
      for (int kx = 0; kx < 3; ++kx) {
        float wv[4];
#pragma unroll
        for (int i = 0; i < 4; ++i) wv[i] = w1p[(i * 64 + ic) * 9 + ky * 3 + kx];
#pragma unroll
        for (int i = 0; i < 4; ++i)
#pragma unroll
          for (int q = 0; q < 4; ++q)
            acc[i][q] = fmaf(wv[i], v[kx + q], acc[i][q]);
      }
    }
  }
#pragma unroll
  for (int i = 0; i < 4; ++i) {
    float bias = b1[oc0 + i];
#pragma unroll
    for (int q = 0; q < 4; ++q) {
      float v = acc[i][q] + bias;
      h1[((b * 256 + oc0 + i) * 64 + y) * 64 + x4 + q] = v > 0.f ? v : 0.f;
    }
  }
}

// -------- conv2 (256->1024, 3x3, relu) fused with conv3 (1x1 1024->64) ------
__global__ __launch_bounds__(256) void conv2_conv3(
    const float* __restrict__ h1, const float* __restrict__ w2,
    const float* __restrict__ b2, const float* __restrict__ w3,
    const float* __restrict__ b3, float* __restrict__ h) {
  int bid = blockIdx.x;
  int y = bid & 63;
  int b = bid >> 6;
  __shared__ float lds[3 * 64 * 66];          // staged h1 tile; r2 aliases it
  float (*r2)[65] = (float(*)[65])lds;        // 64 x 65 = 4160 floats
  int tid = threadIdx.x;
  int xq = tid & 15, tg = tid >> 4;
  int x4 = xq * 4;
  int o0 = tg * 4;
  float oacc[4][4] = {};
  for (int c2b = 0; c2b < 16; ++c2b) {
    int c2_0 = c2b * 64 + tg * 4;
    float acc[4][4] = {};
    for (int c1b = 0; c1b < 4; ++c1b) {
      __syncthreads();  // previous lds/r2 consumers done
      for (int idx = tid; idx < 3 * 64 * 66; idx += 256) {
        int dy  = idx / (64 * 66);
        int rem = idx - dy * (64 * 66);
        int cc  = rem / 66;
        int xx  = rem - cc * 66;
        int yy  = y + dy - 1;
        int xi  = xx - 1;
        float v = 0.f;
        if (yy >= 0 && yy < 64 && xi >= 0 && xi < 64)
          v = h1[((b * 256 + c1b * 64 + cc) * 64 + yy) * 64 + xi];
        lds[idx] = v;
      }
      __syncthreads();
      const float* w2p = w2 + (c2_0 * 256 + c1b * 64) * 9;
      for (int c1 = 0; c1 < 64; ++c1) {
#pragma unroll
        for (int ky = 0; ky < 3; ++ky) {
          const float* lrow = &lds[(ky * 64 + c1) * 66 + x4];
          float v[6];
#pragma unroll
          for (int q = 0; q < 6; ++q) v[q] = lrow[q];
#pragma unroll
          for (int kx = 0; kx < 3; ++kx) {
            float wv[4];
#pragma unroll
            for (int i = 0; i < 4; ++i)
              wv[i] = w2p[(i * 256 + c1) * 9 + ky * 3 + kx];
#pragma unroll
            for (int i = 0; i < 4; ++i)
#pragma unroll
              for (int q = 0; q < 4; ++q)
                acc[i][q] = fmaf(wv[i], v[kx + q], acc[i][q]);
          }
        }
      }
    }
    __syncthreads();  // all conv reads of lds done; safe to overwrite with r2
#pragma unroll
    for (int i = 0; i < 4; ++i) {
      float bias = b2[c2_0 + i];
#pragma unroll
      for (int q = 0; q < 4; ++q) {
        float v = acc[i][q] + bias;
        r2[tg * 4 + i][x4 + q] = v > 0.f ? v : 0.f;
      }
    }
    __syncthreads();
    // conv3 1x1 accumulate: oacc[o][x] += w3[o, c2] * r2[c2][x]
    const float* w3p = w3 + o0 * 1024 + c2b * 64;
    for (int c2 = 0; c2 < 64; ++c2) {
      float wv[4];
#pragma unroll
      for (int i = 0; i < 4; ++i) wv[i] = w3p[i * 1024 + c2];
      float v[4];
#pragma unroll
      for (int q = 0; q < 4; ++q) v[q] = r2[c2][x4 + q];
#pragma unroll
      for (int i = 0; i < 4; ++i)
#pragma unroll
        for (int q = 0; q < 4; ++q)
          oacc[i][q] = fmaf(wv[i], v[q], oacc[i][q]);
    }
  }
#pragma unroll
  for (int i = 0; i < 4; ++i) {
    float bias = b3[o0 + i];
#pragma unroll
    for (int q = 0; q < 4; ++q)
      h[((b * 64 + o0 + i) * 64 + y) * 64 + x4 + q] = oacc[i][q] + bias;
  }
}

// ------------- column sums T[a,c,x] = sum_y h ; pooled = mean(h) -------------
__global__ __launch_bounds__(64) void colsum_pool(
    const float* __restrict__ h, float* __restrict__ T,
    float* __restrict__ pooled) {
  int bc = blockIdx.x;  // a*64 + c
  int x = threadIdx.x;
  const float* p = h + bc * 4096 + x;
  float s = 0.f;
  for (int y = 0; y < 64; ++y) s += p[y * 64];
  T[bc * 64 + x] = s;
  float t = s;
#pragma unroll
  for (int off = 32; off > 0; off >>= 1) t += __shfl_down(t, off);
  if (x == 0) pooled[bc] = t * (1.f / 4096.f);
}

// ---------------- dw[b, c*9+p] = pooled[b] @ wd.T + bd ----------------------
__global__ __launch_bounds__(256) void dyn_w(
    const float* __restrict__ pooled, const float* __restrict__ wd,
    const float* __restrict__ bd, float* __restrict__ dw) {
  int idx = blockIdx.x * 256 + threadIdx.x;
  if (idx >= 4 * 576) return;
  int b = idx / 576, r = idx - b * 576;
  float s = bd[r];
  for (int c = 0; c < 64; ++c) s = fmaf(pooled[b * 64 + c], wd[r * 64 + c], s);
  dw[idx] = s;
}

// ------ xd[a,b,c,x] = sum_{i,j} dw[b,c,3i+j] * S_i[a,c,x+j-1] ---------------
__global__ __launch_bounds__(256) void xd_kernel(
    const float* __restrict__ h, const float* __restrict__ T,
    const float* __restrict__ dw, float* __restrict__ xd) {
  int idx = blockIdx.x * 256 + threadIdx.x;  // 65536
  int x  = idx & 63;
  int c  = (idx >> 6) & 63;
  int bb = (idx >> 12) & 3;
  int a  = idx >> 14;
  const float* dwp = dw + bb * 576 + c * 9;
  const float* Tp  = T + (a * 64 + c) * 64;
  const float* h0  = h + (a * 64 + c) * 4096;  // row 0
  const float* h63 = h0 + 63 * 64;             // row 63
  float acc = 0.f;
#pragma unroll
  for (int j = 0; j < 3; ++j) {
    int xi = x + j - 1;
    if (xi >= 0 && xi < 64) {
      float t  = Tp[xi];
      float S0 = t - h63[xi];   // rows -1..62
      float S2 = t - h0[xi];    // rows 1..64
      acc = fmaf(dwp[j],     S0, acc);
      acc = fmaf(dwp[3 + j], t,  acc);
      acc = fmaf(dwp[6 + j], S2, acc);
    }
  }
  xd[idx] = acc;
}

// -------- out_pre[a,o,c,x] = sum_b xd[a,b,c,x] * w4[o,b] + b4[o] ------------
__global__ __launch_bounds__(256) void outpre_kernel(
    const float* __restrict__ xd, const float* __restrict__ w4,
    const float* __restrict__ b4, float* __restrict__ out) {
  int idx = blockIdx.x * 256 + threadIdx.x;  // 1048576
  int x = idx & 63;
  int c = (idx >> 6) & 63;
  int o = (idx >> 12) & 63;
  int a = idx >> 18;
  const float* xp = xd + (a * 4 * 64 + c) * 64 + x;  // stride 4096 between b
  float s = b4[o];
#pragma unroll
  for (int bb = 0; bb < 4; ++bb) s = fmaf(xp[bb * 4096], w4[o * 4 + bb], s);
  out[idx] = s;
}

// ----------------- batchnorm stats per o over (a, c, x) ---------------------
__global__ __launch_bounds__(256) void bnstats_kernel(
    const float* __restrict__ out, float* __restrict__ stats) {
  int o = blockIdx.x;
  int tid = threadIdx.x;
  float s = 0.f, sq = 0.f;
  for (int i = tid; i < 4 * 64 * 64; i += 256) {
    int a = i >> 12;
    int rem = i & 4095;
    float v = out[a * 262144 + o * 4096 + rem];
    s += v;
    sq = fmaf(v, v, sq);
  }
  __shared__ float ls[256], lq[256];
  ls[tid] = s; lq[tid] = sq;
  __syncthreads();
  for (int off = 128; off > 0; off >>= 1) {
    if (tid < off) { ls[tid] += ls[tid + off]; lq[tid] += lq[tid + off]; }
    __syncthreads();
  }
  if (tid == 0) {
    float mean = ls[0] * (1.f / 16384.f);
    float var  = lq[0] * (1.f / 16384.f) - mean * mean;
    stats[o * 2]     = mean;
    stats[o * 2 + 1] = rsqrtf(var + 1e-5f);
  }
}

// ----------------------- batchnorm apply + affine ---------------------------
__global__ __launch_bounds__(256) void bnapply_kernel(
    float* __restrict__ out, const float* __restrict__ stats,
    const float* __restrict__ gamma, const float* __restrict__ beta) {
  int idx = blockIdx.x * 256 + threadIdx.x;
  int o = (idx >> 12) & 63;
  float mean = stats[o * 2], rstd = stats[o * 2 + 1];
  out[idx] = (out[idx] - mean) * rstd * gamma[o] + beta[o];
}

extern "C" void kernel_launch(void* const* d_in, const int* in_sizes, int n_in,
                              void* d_out, int out_size, void* d_ws,
                              size_t ws_size, hipStream_t stream) {
  const float* x     = (const float*)d_in[0];
  const float* w1    = (const float*)d_in[1];
  const float* b1    = (const float*)d_in[2];
  const float* w2    = (const float*)d_in[3];
  const float* b2    = (const float*)d_in[4];
  const float* w3    = (const float*)d_in[5];
  const float* b3    = (const float*)d_in[6];
  const float* wd    = (const float*)d_in[7];
  const float* bd    = (const float*)d_in[8];
  const float* w4    = (const float*)d_in[9];
  const float* b4    = (const float*)d_in[10];
  const float* gamma = (const float*)d_in[11];
  const float* beta  = (const float*)d_in[12];
  float* out = (float*)d_out;
  float* ws  = (float*)d_ws;

  float* h1b    = ws + OFF_H1;
  float* hb     = ws + OFF_H;
  float* Tb     = ws + OFF_T;
  float* pooled = ws + OFF_POOLED;
  float* dwb    = ws + OFF_DW;
  float* xdb    = ws + OFF_XD;
  float* stats  = ws + OFF_STATS;

  conv1_relu<<<1024, 256, 0, stream>>>(x, w1, b1, h1b);
  conv2_conv3<<<256, 256, 0, stream>>>(h1b, w2, b2, w3, b3, hb);
  colsum_pool<<<256, 64, 0, stream>>>(hb, Tb, pooled);
  dyn_w<<<9, 256, 0, stream>>>(pooled, wd, bd, dwb);
  xd_kernel<<<256, 256, 0, stream>>>(hb, Tb, dwb, xdb);
  outpre_kernel<<<4096, 256, 0, stream>>>(xdb, w4, b4, out);
  bnstats_kernel<<<64, 256, 0, stream>>>(out, stats);
  bnapply_kernel<<<4096, 256, 0, stream>>>(out, stats, gamma, beta);
}

// Round 2
// 286.446 us; speedup vs baseline: 8.7413x; 8.7413x over previous
//
#include <hip/hip_runtime.h>
#include <hip/hip_bf16.h>
#include <math.h>

typedef unsigned short ushort;
typedef __attribute__((ext_vector_type(8))) short bf16x8;
typedef __attribute__((ext_vector_type(4))) float f32x4;
typedef __attribute__((ext_vector_type(8))) ushort ushort8;

__device__ inline ushort f2bf(float f) {
  __hip_bfloat16 h = __float2bfloat16(f);
  return *reinterpret_cast<ushort*>(&h);
}

// ---------------- pack x: NCHW f32 -> NHWC bf16 [b][y][x][64] ---------------
__global__ __launch_bounds__(256) void pack_x_nhwc(
    const float* __restrict__ x, ushort* __restrict__ xn) {
  int blk = blockIdx.x;           // b*64 + y
  int b = blk >> 6, y = blk & 63;
  __shared__ float ld[64][65];
  int tid = threadIdx.x;
  int xx = tid & 63;
#pragma unroll
  for (int i = 0; i < 16; ++i) {
    int c = i * 4 + (tid >> 6);
    ld[c][xx] = x[((b * 64 + c) * 64 + y) * 64 + xx];
  }
  __syncthreads();
  for (int u = tid; u < 64 * 8; u += 256) {
    int xp = u >> 3, cg = u & 7;
    ushort8 v;
#pragma unroll
    for (int j = 0; j < 8; ++j) v[j] = f2bf(ld[cg * 8 + j][xp]);
    *reinterpret_cast<ushort8*>(&xn[((b * 64 + y) * 64 + xp) * 64 + cg * 8]) = v;
  }
}

// --------- pack w (OIHW f32) -> [tap][oc][cin] bf16, thread per (oc,cin) ----
__global__ __launch_bounds__(256) void pack_w(
    const float* __restrict__ w, ushort* __restrict__ wp, int OC, int CIN) {
  int idx = blockIdx.x * 256 + threadIdx.x;
  if (idx >= OC * CIN) return;
  float v[9];
#pragma unroll
  for (int t = 0; t < 9; ++t) v[t] = w[idx * 9 + t];
  int oc = idx / CIN, c = idx - oc * CIN;
#pragma unroll
  for (int t = 0; t < 9; ++t) wp[(t * OC + oc) * CIN + c] = f2bf(v[t]);
}

__global__ __launch_bounds__(256) void pack_w3k(
    const float* __restrict__ w3, ushort* __restrict__ wp) {
  int idx = blockIdx.x * 256 + threadIdx.x;  // 65536
  wp[idx] = f2bf(w3[idx]);
}

// --------------------- implicit-GEMM conv via MFMA --------------------------
// in_nhwc: [16384 px][CIN] bf16; wpack: [TAPS][NOC][CIN] bf16.
// C[px][oc] = sum_k im2col(in)[px][k] * w[oc][k], k = (tap, cin)
template<int C1B, int TAPS, int NOC, int WMF, int WNF, bool RELU, bool NCHW_OUT>
__global__ __launch_bounds__(256) void conv_gemm(
    const ushort* __restrict__ in_nhwc, const ushort* __restrict__ wpack,
    const float* __restrict__ bias, ushort* __restrict__ out_nhwc,
    float* __restrict__ out_nchw) {
  constexpr int BM = 2 * WMF * 16;
  constexpr int BN = 2 * WNF * 16;
  constexpr int CIN = C1B * 64;
  constexpr int ROWS = BM / 64 + 2;
  __shared__ ushort Alds[ROWS * 66 * 72];  // [rowslot][xslot(=x+1)][64c + 8 pad]
  __shared__ ushort Blds[BN * 72];         // [oc][64c + 8 pad]
  int tid = threadIdx.x;
  int P0 = blockIdx.x * BM;
  int b = P0 >> 12;
  int y0 = (P0 & 4095) >> 6;
  int ocB = blockIdx.y * BN;
  int w = tid >> 6, lane = tid & 63;
  int wm = w >> 1, wn = w & 1;
  int lrow = lane & 15, lk = lane >> 4;
  f32x4 acc[WMF][WNF] = {};

#pragma unroll 1
  for (int cb = 0; cb < C1B; ++cb) {
    int c0 = cb * 64;
#pragma unroll 1
    for (int t = 0; t < TAPS; ++t) {
      int ky = (TAPS == 9) ? t / 3 : 1;
      int kx = (TAPS == 9) ? t % 3 : 1;
      __syncthreads();  // previous MFMA reads done
      if (t == 0) {     // stage A tile (reused across taps)
        for (int u = tid; u < ROWS * 66 * 8; u += 256) {
          int ry = u / (66 * 8);
          int rem = u - ry * (66 * 8);
          int xs = rem >> 3, cg = rem & 7;
          int yy = y0 + ry - 1;
          int xx = xs - 1;
          ushort8 v = {0, 0, 0, 0, 0, 0, 0, 0};
          if (yy >= 0 && yy < 64 && xx >= 0 && xx < 64)
            v = *reinterpret_cast<const ushort8*>(
                &in_nhwc[((b * 64 + yy) * 64 + xx) * CIN + c0 + cg * 8]);
          *reinterpret_cast<ushort8*>(&Alds[(ry * 66 + xs) * 72 + cg * 8]) = v;
        }
      }
      // stage B tile (weights for this tap / c-block)
      for (int u = tid; u < BN * 8; u += 256) {
        int oc = u >> 3, cg = u & 7;
        ushort8 v = *reinterpret_cast<const ushort8*>(
            &wpack[(t * NOC + ocB + oc) * CIN + c0 + cg * 8]);
        *reinterpret_cast<ushort8*>(&Blds[oc * 72 + cg * 8]) = v;
      }
      __syncthreads();
#pragma unroll
      for (int ks = 0; ks < 2; ++ks) {
        int kb = ks * 32 + lk * 8;
        bf16x8 af[WMF], bfr[WNF];
#pragma unroll
        for (int mf = 0; mf < WMF; ++mf) {
          int m = wm * (WMF * 16) + mf * 16 + lrow;
          int r = m >> 6, xp = m & 63;
          af[mf] = *reinterpret_cast<const bf16x8*>(
              &Alds[((r + ky) * 66 + (xp + kx)) * 72 + kb]);
        }
#pragma unroll
        for (int nf = 0; nf < WNF; ++nf) {
          int oc = wn * (WNF * 16) + nf * 16 + lrow;
          bfr[nf] = *reinterpret_cast<const bf16x8*>(&Blds[oc * 72 + kb]);
        }
#pragma unroll
        for (int mf = 0; mf < WMF; ++mf)
#pragma unroll
          for (int nf = 0; nf < WNF; ++nf)
            acc[mf][nf] = __builtin_amdgcn_mfma_f32_16x16x32_bf16(
                af[mf], bfr[nf], acc[mf][nf], 0, 0, 0);
      }
    }
  }
  // epilogue
#pragma unroll
  for (int nf = 0; nf < WNF; ++nf) {
    int oc = ocB + wn * (WNF * 16) + nf * 16 + lrow;
    float bv = bias[oc];
#pragma unroll
    for (int mf = 0; mf < WMF; ++mf) {
      int m0 = wm * (WMF * 16) + mf * 16 + lk * 4;
      if (!NCHW_OUT) {
#pragma unroll
        for (int r = 0; r < 4; ++r) {
          float vv = acc[mf][nf][r] + bv;
          if (RELU) vv = vv > 0.f ? vv : 0.f;
          out_nhwc[(P0 + m0 + r) * NOC + oc] = f2bf(vv);
        }
      } else {
        int px = P0 + m0;
        int bb = px >> 12, pl = px & 4095;
        float4 o;
        o.x = acc[mf][nf][0] + bv;
        o.y = acc[mf][nf][1] + bv;
        o.z = acc[mf][nf][2] + bv;
        o.w = acc[mf][nf][3] + bv;
        *reinterpret_cast<float4*>(&out_nchw[(bb * NOC + oc) * 4096 + pl]) = o;
      }
    }
  }
}

// ------------- column sums T[a,c,x] = sum_y h ; pooled = mean(h) -------------
__global__ __launch_bounds__(64) void colsum_pool(
    const float* __restrict__ h, float* __restrict__ T,
    float* __restrict__ pooled) {
  int bc = blockIdx.x;  // a*64 + c
  int x = threadIdx.x;
  const float* p = h + bc * 4096 + x;
  float s = 0.f;
  for (int y = 0; y < 64; ++y) s += p[y * 64];
  T[bc * 64 + x] = s;
  float t = s;
#pragma unroll
  for (int off = 32; off > 0; off >>= 1) t += __shfl_down(t, off);
  if (x == 0) pooled[bc] = t * (1.f / 4096.f);
}

// ---------------- dw[b, c*9+p] = pooled[b] @ wd.T + bd ----------------------
__global__ __launch_bounds__(256) void dyn_w(
    const float* __restrict__ pooled, const float* __restrict__ wd,
    const float* __restrict__ bd, float* __restrict__ dw) {
  int idx = blockIdx.x * 256 + threadIdx.x;
  if (idx >= 4 * 576) return;
  int b = idx / 576, r = idx - b * 576;
  float s = bd[r];
  for (int c = 0; c < 64; ++c) s = fmaf(pooled[b * 64 + c], wd[r * 64 + c], s);
  dw[idx] = s;
}

// ------ xd[a,b,c,x] = sum_{i,j} dw[b,c,3i+j] * S_i[a,c,x+j-1] ---------------
__global__ __launch_bounds__(256) void xd_kernel(
    const float* __restrict__ h, const float* __restrict__ T,
    const float* __restrict__ dw, float* __restrict__ xd) {
  int idx = blockIdx.x * 256 + threadIdx.x;  // 65536
  int x = idx & 63;
  int c = (idx >> 6) & 63;
  int bb = (idx >> 12) & 3;
  int a = idx >> 14;
  const float* dwp = dw + bb * 576 + c * 9;
  const float* Tp = T + (a * 64 + c) * 64;
  const float* h0 = h + (a * 64 + c) * 4096;
  const float* h63 = h0 + 63 * 64;
  float acc = 0.f;
#pragma unroll
  for (int j = 0; j < 3; ++j) {
    int xi = x + j - 1;
    if (xi >= 0 && xi < 64) {
      float t = Tp[xi];
      float S0 = t - h63[xi];
      float S2 = t - h0[xi];
      acc = fmaf(dwp[j], S0, acc);
      acc = fmaf(dwp[3 + j], t, acc);
      acc = fmaf(dwp[6 + j], S2, acc);
    }
  }
  xd[idx] = acc;
}

// -------- out_pre[a,o,c,x] = sum_b xd[a,b,c,x] * w4[o,b] + b4[o] ------------
__global__ __launch_bounds__(256) void outpre_kernel(
    const float* __restrict__ xd, const float* __restrict__ w4,
    const float* __restrict__ b4, float* __restrict__ out) {
  int idx = blockIdx.x * 256 + threadIdx.x;  // 1048576
  int x = idx & 63;
  int c = (idx >> 6) & 63;
  int o = (idx >> 12) & 63;
  int a = idx >> 18;
  const float* xp = xd + (a * 4 * 64 + c) * 64 + x;
  float s = b4[o];
#pragma unroll
  for (int bb = 0; bb < 4; ++bb) s = fmaf(xp[bb * 4096], w4[o * 4 + bb], s);
  out[idx] = s;
}

// ----------------- batchnorm stats per o over (a, c, x) ---------------------
__global__ __launch_bounds__(256) void bnstats_kernel(
    const float* __restrict__ out, float* __restrict__ stats) {
  int o = blockIdx.x;
  int tid = threadIdx.x;
  float s = 0.f, sq = 0.f;
  for (int i = tid; i < 4 * 64 * 64; i += 256) {
    int a = i >> 12;
    int rem = i & 4095;
    float v = out[a * 262144 + o * 4096 + rem];
    s += v;
    sq = fmaf(v, v, sq);
  }
  __shared__ float ls[256], lq[256];
  ls[tid] = s; lq[tid] = sq;
  __syncthreads();
  for (int off = 128; off > 0; off >>= 1) {
    if (tid < off) { ls[tid] += ls[tid + off]; lq[tid] += lq[tid + off]; }
    __syncthreads();
  }
  if (tid == 0) {
    float mean = ls[0] * (1.f / 16384.f);
    float var = lq[0] * (1.f / 16384.f) - mean * mean;
    stats[o * 2] = mean;
    stats[o * 2 + 1] = rsqrtf(var + 1e-5f);
  }
}

__global__ __launch_bounds__(256) void bnapply_kernel(
    float* __restrict__ out, const float* __restrict__ stats,
    const float* __restrict__ gamma, const float* __restrict__ beta) {
  int idx = blockIdx.x * 256 + threadIdx.x;
  int o = (idx >> 12) & 63;
  float mean = stats[o * 2], rstd = stats[o * 2 + 1];
  out[idx] = (out[idx] - mean) * rstd * gamma[o] + beta[o];
}

// ---------------------------------------------------------------------------
extern "C" void kernel_launch(void* const* d_in, const int* in_sizes, int n_in,
                              void* d_out, int out_size, void* d_ws,
                              size_t ws_size, hipStream_t stream) {
  const float* x     = (const float*)d_in[0];
  const float* w1    = (const float*)d_in[1];
  const float* b1    = (const float*)d_in[2];
  const float* w2    = (const float*)d_in[3];
  const float* b2    = (const float*)d_in[4];
  const float* w3    = (const float*)d_in[5];
  const float* b3    = (const float*)d_in[6];
  const float* wd    = (const float*)d_in[7];
  const float* bd    = (const float*)d_in[8];
  const float* w4    = (const float*)d_in[9];
  const float* b4    = (const float*)d_in[10];
  const float* gamma = (const float*)d_in[11];
  const float* beta  = (const float*)d_in[12];
  float* out = (float*)d_out;

  // workspace carve (ushort region, then float region)
  ushort* us = (ushort*)d_ws;
  ushort* xn   = us;                       // 1,048,576
  ushort* h1n  = xn + 1048576;             // 4,194,304
  ushort* h2n  = h1n + 4194304;            // 16,777,216
  ushort* w1p  = h2n + 16777216;           // 147,456
  ushort* w2p  = w1p + 147456;             // 2,359,296
  ushort* w3p  = w2p + 2359296;            // 65,536
  float* fbase = (float*)(w3p + 65536);
  float* Tb     = fbase;                   // 16384
  float* pooled = Tb + 16384;              // 256
  float* dwb    = pooled + 256;            // 2304
  float* xdb    = dwb + 2304;              // 65536
  float* stats  = xdb + 65536;             // 128
  float* hb     = out;                     // conv3 out lives in d_out (dead by outpre)

  pack_x_nhwc<<<256, 256, 0, stream>>>(x, xn);
  pack_w<<<64, 256, 0, stream>>>(w1, w1p, 256, 64);
  pack_w<<<1024, 256, 0, stream>>>(w2, w2p, 1024, 256);
  pack_w3k<<<256, 256, 0, stream>>>(w3, w3p);

  conv_gemm<1, 9, 256, 4, 4, true, false>
      <<<dim3(128, 2), 256, 0, stream>>>(xn, w1p, b1, h1n, nullptr);
  conv_gemm<4, 9, 1024, 4, 4, true, false>
      <<<dim3(128, 8), 256, 0, stream>>>(h1n, w2p, b2, h2n, nullptr);
  conv_gemm<16, 1, 64, 2, 2, false, true>
      <<<dim3(256, 1), 256, 0, stream>>>(h2n, w3p, b3, nullptr, hb);

  colsum_pool<<<256, 64, 0, stream>>>(hb, Tb, pooled);
  dyn_w<<<9, 256, 0, stream>>>(pooled, wd, bd, dwb);
  xd_kernel<<<256, 256, 0, stream>>>(hb, Tb, dwb, xdb);
  outpre_kernel<<<4096, 256, 0, stream>>>(xdb, w4, b4, out);
  bnstats_kernel<<<64, 256, 0, stream>>>(out, stats);
  bnapply_kernel<<<4096, 256, 0, stream>>>(out, stats, gamma, beta);
}

// Round 3
// 184.488 us; speedup vs baseline: 13.5722x; 1.5527x over previous
//
#include <hip/hip_runtime.h>
#include <hip/hip_bf16.h>
#include <math.h>

typedef unsigned short ushort;
typedef __attribute__((ext_vector_type(8))) short bf16x8;
typedef __attribute__((ext_vector_type(4))) float f32x4;
typedef __attribute__((ext_vector_type(8))) ushort ushort8;

__device__ inline ushort f2bf(float f) {
  __hip_bfloat16 h = __float2bfloat16(f);
  return *reinterpret_cast<ushort*>(&h);
}

typedef __attribute__((address_space(3))) unsigned int lds_u32;
typedef __attribute__((address_space(1))) const unsigned int glb_u32;
__device__ __forceinline__ void gl2lds16(const ushort* g, ushort* l) {
  __builtin_amdgcn_global_load_lds((glb_u32*)g, (lds_u32*)l, 16, 0, 0);
}

#define S_BARRIER asm volatile("s_barrier" ::: "memory")
#define WAITV0 asm volatile("s_waitcnt vmcnt(0)" ::: "memory")
#define WAITV2 asm volatile("s_waitcnt vmcnt(2)" ::: "memory")

// ============================ pack_all =====================================
// blocks [0,264): x NCHW f32 -> padded NHWC bf16 [b][66][66][64] (borders 0)
// blocks [264,328): w1 OIHW -> [tap][256][64]
// blocks [328,1352): w2 OIHW -> [tap][1024][256]
// blocks [1352,1608): w3 flat bf16 copy [64][1024]
// blocks [1608,2648): zero borders of h1n_pad [b][66][66][256]
__global__ __launch_bounds__(256) void pack_all(
    const float* __restrict__ x, const float* __restrict__ w1,
    const float* __restrict__ w2, const float* __restrict__ w3,
    ushort* __restrict__ xn_pad, ushort* __restrict__ w1p,
    ushort* __restrict__ w2p, ushort* __restrict__ w3p,
    ushort* __restrict__ h1n_pad) {
  int blk = blockIdx.x;
  int tid = threadIdx.x;
  __shared__ float ld[64][65];
  if (blk < 264) {
    int b = blk / 66, yp = blk % 66;
    ushort* dst = xn_pad + (size_t)(b * 66 + yp) * 66 * 64;
    if (yp == 0 || yp == 65) {
      for (int i = tid; i < 66 * 64; i += 256) dst[i] = 0;
      return;
    }
    int y = yp - 1;
    int xx = tid & 63;
#pragma unroll
    for (int i = 0; i < 16; ++i) {
      int c = i * 4 + (tid >> 6);
      ld[c][xx] = x[((b * 64 + c) * 64 + y) * 64 + xx];
    }
    __syncthreads();
    for (int i = tid; i < 2 * 64; i += 256) {
      int side = i >> 6, c = i & 63;
      dst[(side ? 65 : 0) * 64 + c] = 0;
    }
    for (int u = tid; u < 64 * 8; u += 256) {
      int xp = u >> 3, cg = u & 7;
      ushort8 v;
#pragma unroll
      for (int j = 0; j < 8; ++j) v[j] = f2bf(ld[cg * 8 + j][xp]);
      *reinterpret_cast<ushort8*>(&dst[(xp + 1) * 64 + cg * 8]) = v;
    }
  } else if (blk < 328) {
    int idx = (blk - 264) * 256 + tid;  // OC=256, CIN=64
    float v[9];
#pragma unroll
    for (int t = 0; t < 9; ++t) v[t] = w1[idx * 9 + t];
    int oc = idx >> 6, c = idx & 63;
#pragma unroll
    for (int t = 0; t < 9; ++t) w1p[(t * 256 + oc) * 64 + c] = f2bf(v[t]);
  } else if (blk < 1352) {
    int idx = (blk - 328) * 256 + tid;  // OC=1024, CIN=256
    float v[9];
#pragma unroll
    for (int t = 0; t < 9; ++t) v[t] = w2[(size_t)idx * 9 + t];
    int oc = idx >> 8, c = idx & 255;
#pragma unroll
    for (int t = 0; t < 9; ++t) w2p[((size_t)t * 1024 + oc) * 256 + c] = f2bf(v[t]);
  } else if (blk < 1608) {
    int idx = (blk - 1352) * 256 + tid;
    w3p[idx] = f2bf(w3[idx]);
  } else {
    int k = blk - 1608;  // 0..1039
    int b = k / 260, p = k % 260;
    int yp, xp;
    if (p < 66) { yp = 0; xp = p; }
    else if (p < 132) { yp = 65; xp = p - 66; }
    else if (p < 196) { yp = p - 132 + 1; xp = 0; }
    else { yp = p - 196 + 1; xp = 65; }
    h1n_pad[((size_t)(b * 66 + yp) * 66 + xp) * 256 + tid] = 0;
  }
}

// ================= pipelined implicit-GEMM conv (3x3, pad 1) ================
// in_pad: [b][66][66][CIN] bf16, zero borders. wpack: [9][NOC][CIN].
// BM=256 (4 image rows), BN=128. 8 waves (4M x 2N), wave tile 64x64.
// K-step = (cb, tap) = 64. A staged per cb (swizzled), B triple-buffered with
// global_load_lds prefetch 2 steps ahead + counted vmcnt.
template<int C1B, int NOC, bool POUT>
__global__ __launch_bounds__(512, 2) void conv_gemm2(
    const ushort* __restrict__ in_pad, const ushort* __restrict__ wpack,
    const float* __restrict__ bias, ushort* __restrict__ outp) {
  constexpr int CIN = C1B * 64;
  constexpr int NSTEP = C1B * 9;
  extern __shared__ ushort lds[];
  ushort* Araw = lds;            // 3584 chunks x 16B = 57344 B (396 rows used)
  ushort* Bb = lds + 28672;      // 3 x 8192 ushorts = 49152 B
  int tid = threadIdx.x;
  int wid = tid >> 6, lane = tid & 63;
  int lrow = lane & 15, lk = lane >> 4;
  int wm = wid >> 1, wn = wid & 1;
  int P0 = blockIdx.x * 256;
  int b = P0 >> 12;
  int y0 = (P0 & 4095) >> 6;
  int ocB = blockIdx.y * 128;
  f32x4 acc[4][4] = {};

  auto stageA = [&](int cb) {
    const ushort* asrc = in_pad + (size_t)(b * 66 + y0) * 66 * CIN + cb * 64;
#pragma unroll
    for (int it = 0; it < 7; ++it) {
      int basech = it * 512 + wid * 64;
      int ch = basech + lane;
      int ry = ch / 528, rem = ch % 528;
      int xs = rem >> 3, cg = rem & 7;
      int cgp = cg ^ (xs & 7);
      gl2lds16(asrc + (size_t)(ry * 66 + xs) * CIN + cgp * 8,
               Araw + basech * 8);
    }
  };
  auto stageB = [&](int sstep, int q) {
    int st = sstep / C1B >= 0 ? sstep % 9 : 0;
    st = sstep % 9;
    int scb = sstep / 9;
    const ushort* wsrc = wpack + ((size_t)st * NOC + ocB) * CIN + scb * 64;
    ushort* dbase = Bb + q * 8192;
#pragma unroll
    for (int it = 0; it < 2; ++it) {
      int basech = it * 512 + wid * 64;
      int ch = basech + lane;
      int oc = ch >> 3, cg = ch & 7;
      int cgp = cg ^ (oc & 7);
      gl2lds16(wsrc + (size_t)oc * CIN + cgp * 8, dbase + basech * 8);
    }
  };

  // prologue
  stageA(0);
  stageB(0, 0);
  stageB(1, 1);
  WAITV2;
  S_BARRIER;

#pragma unroll 1
  for (int cb = 0; cb < C1B; ++cb) {
#pragma unroll 1
    for (int t = 0; t < 9; ++t) {
      int step = cb * 9 + t;
      int cur = step % 3;
      if (step + 2 < NSTEP) stageB(step + 2, (step + 2) % 3);
      int ky = t / 3, kx = t - ky * 3;
      bf16x8 af[4][2], bfv[4][2];
      const ushort* bcur = Bb + cur * 8192;
#pragma unroll
      for (int ks = 0; ks < 2; ++ks) {
#pragma unroll
        for (int mf = 0; mf < 4; ++mf) {
          int xs = mf * 16 + lrow + kx;
          int row = (wm + ky) * 66 + xs;
          int kboff = (ks * 64 + lk * 16) ^ ((xs & 7) << 4);
          af[mf][ks] =
              *reinterpret_cast<const bf16x8*>(Araw + row * 64 + (kboff >> 1));
        }
#pragma unroll
        for (int nf = 0; nf < 4; ++nf) {
          int oc_l = wn * 64 + nf * 16 + lrow;
          int kboff = (ks * 64 + lk * 16) ^ ((oc_l & 7) << 4);
          bfv[nf][ks] =
              *reinterpret_cast<const bf16x8*>(bcur + oc_l * 64 + (kboff >> 1));
        }
      }
#pragma unroll
      for (int ks = 0; ks < 2; ++ks)
#pragma unroll
        for (int mf = 0; mf < 4; ++mf)
#pragma unroll
          for (int nf = 0; nf < 4; ++nf)
            acc[mf][nf] = __builtin_amdgcn_mfma_f32_16x16x32_bf16(
                af[mf][ks], bfv[nf][ks], acc[mf][nf], 0, 0, 0);
      if (t == 8 && cb + 1 < C1B) {
        S_BARRIER;          // all waves done reading Araw
        stageA(cb + 1);
        WAITV0;
        S_BARRIER;
      } else if (step + 2 < NSTEP) {
        WAITV2;             // B(step+1) landed; B(step+2) may fly
        S_BARRIER;
      } else {
        WAITV0;
        S_BARRIER;
      }
    }
  }

  // epilogue: bias + relu, bf16 out
#pragma unroll
  for (int nf = 0; nf < 4; ++nf) {
    int oc = ocB + wn * 64 + nf * 16 + lrow;
    float bv = bias[oc];
#pragma unroll
    for (int mf = 0; mf < 4; ++mf) {
      int m0 = wm * 64 + mf * 16 + lk * 4;
#pragma unroll
      for (int r = 0; r < 4; ++r) {
        float vv = acc[mf][nf][r] + bv;
        vv = vv > 0.f ? vv : 0.f;
        int px = P0 + m0 + r;
        if (POUT) {
          int bb = px >> 12, yy = (px >> 6) & 63, xx = px & 63;
          outp[((size_t)(bb * 66 + yy + 1) * 66 + xx + 1) * NOC + oc] = f2bf(vv);
        } else {
          outp[(size_t)px * NOC + oc] = f2bf(vv);
        }
      }
    }
  }
}

// ============ conv3: round-2 implicit GEMM (1x1, 1024->64, NCHW f32) ========
template<int C1B, int TAPS, int NOC, int WMF, int WNF, bool RELU, bool NCHW_OUT>
__global__ __launch_bounds__(256) void conv_gemm_s(
    const ushort* __restrict__ in_nhwc, const ushort* __restrict__ wpack,
    const float* __restrict__ bias, ushort* __restrict__ out_nhwc,
    float* __restrict__ out_nchw) {
  constexpr int BM = 2 * WMF * 16;
  constexpr int BN = 2 * WNF * 16;
  constexpr int CIN = C1B * 64;
  constexpr int ROWS = BM / 64 + 2;
  __shared__ ushort Alds[ROWS * 66 * 72];
  __shared__ ushort Blds[BN * 72];
  int tid = threadIdx.x;
  int P0 = blockIdx.x * BM;
  int b = P0 >> 12;
  int y0 = (P0 & 4095) >> 6;
  int ocB = blockIdx.y * BN;
  int w = tid >> 6, lane = tid & 63;
  int wm = w >> 1, wn = w & 1;
  int lrow = lane & 15, lk = lane >> 4;
  f32x4 acc[WMF][WNF] = {};
#pragma unroll 1
  for (int cb = 0; cb < C1B; ++cb) {
    int c0 = cb * 64;
#pragma unroll 1
    for (int t = 0; t < TAPS; ++t) {
      int ky = (TAPS == 9) ? t / 3 : 1;
      int kx = (TAPS == 9) ? t % 3 : 1;
      __syncthreads();
      if (t == 0) {
        for (int u = tid; u < ROWS * 66 * 8; u += 256) {
          int ry = u / (66 * 8);
          int rem = u - ry * (66 * 8);
          int xs = rem >> 3, cg = rem & 7;
          int yy = y0 + ry - 1;
          int xx = xs - 1;
          ushort8 v = {0, 0, 0, 0, 0, 0, 0, 0};
          if (yy >= 0 && yy < 64 && xx >= 0 && xx < 64)
            v = *reinterpret_cast<const ushort8*>(
                &in_nhwc[((size_t)((b * 64 + yy) * 64 + xx)) * CIN + c0 + cg * 8]);
          *reinterpret_cast<ushort8*>(&Alds[(ry * 66 + xs) * 72 + cg * 8]) = v;
        }
      }
      for (int u = tid; u < BN * 8; u += 256) {
        int oc = u >> 3, cg = u & 7;
        ushort8 v = *reinterpret_cast<const ushort8*>(
            &wpack[((size_t)t * NOC + ocB + oc) * CIN + c0 + cg * 8]);
        *reinterpret_cast<ushort8*>(&Blds[oc * 72 + cg * 8]) = v;
      }
      __syncthreads();
#pragma unroll
      for (int ks = 0; ks < 2; ++ks) {
        int kb = ks * 32 + lk * 8;
        bf16x8 af[WMF], bfr[WNF];
#pragma unroll
        for (int mf = 0; mf < WMF; ++mf) {
          int m = wm * (WMF * 16) + mf * 16 + lrow;
          int r = m >> 6, xp = m & 63;
          af[mf] = *reinterpret_cast<const bf16x8*>(
              &Alds[((r + ky) * 66 + (xp + kx)) * 72 + kb]);
        }
#pragma unroll
        for (int nf = 0; nf < WNF; ++nf) {
          int oc = wn * (WNF * 16) + nf * 16 + lrow;
          bfr[nf] = *reinterpret_cast<const bf16x8*>(&Blds[oc * 72 + kb]);
        }
#pragma unroll
        for (int mf = 0; mf < WMF; ++mf)
#pragma unroll
          for (int nf = 0; nf < WNF; ++nf)
            acc[mf][nf] = __builtin_amdgcn_mfma_f32_16x16x32_bf16(
                af[mf], bfr[nf], acc[mf][nf], 0, 0, 0);
      }
    }
  }
#pragma unroll
  for (int nf = 0; nf < WNF; ++nf) {
    int oc = ocB + wn * (WNF * 16) + nf * 16 + lrow;
    float bv = bias[oc];
#pragma unroll
    for (int mf = 0; mf < WMF; ++mf) {
      int m0 = wm * (WMF * 16) + mf * 16 + lk * 4;
      int px = P0 + m0;
      int bb = px >> 12, pl = px & 4095;
      float4 o;
      o.x = acc[mf][nf][0] + bv;
      o.y = acc[mf][nf][1] + bv;
      o.z = acc[mf][nf][2] + bv;
      o.w = acc[mf][nf][3] + bv;
      *reinterpret_cast<float4*>(&out_nchw[((size_t)(bb * NOC + oc)) * 4096 + pl]) = o;
    }
  }
}

// ------------- column sums T[a,c,x] = sum_y h ; pooled = mean(h) -------------
__global__ __launch_bounds__(64) void colsum_pool(
    const float* __restrict__ h, float* __restrict__ T,
    float* __restrict__ pooled) {
  int bc = blockIdx.x;
  int x = threadIdx.x;
  const float* p = h + (size_t)bc * 4096 + x;
  float s = 0.f;
  for (int y = 0; y < 64; ++y) s += p[y * 64];
  T[bc * 64 + x] = s;
  float t = s;
#pragma unroll
  for (int off = 32; off > 0; off >>= 1) t += __shfl_down(t, off);
  if (x == 0) pooled[bc] = t * (1.f / 4096.f);
}

// ---- xd[a,b,c,x]; dw computed in-block from pooled (fused dyn_w) -----------
__global__ __launch_bounds__(256) void xd_kernel(
    const float* __restrict__ h, const float* __restrict__ T,
    const float* __restrict__ pooled, const float* __restrict__ wd,
    const float* __restrict__ bd, float* __restrict__ xd) {
  int tid = threadIdx.x;
  int idx = blockIdx.x * 256 + tid;
  int c0 = ((idx >> 6) & 63) & ~3;
  int bb = (idx >> 12) & 3;
  __shared__ float dwl[36];
  if (tid < 36) {
    int cj = tid / 9, p = tid % 9;
    int r = (c0 + cj) * 9 + p;
    float s = bd[r];
    for (int cc = 0; cc < 64; ++cc)
      s = fmaf(pooled[bb * 64 + cc], wd[r * 64 + cc], s);
    dwl[tid] = s;
  }
  __syncthreads();
  int x = idx & 63;
  int c = (idx >> 6) & 63;
  int a = idx >> 14;
  const float* dwp = dwl + (c & 3) * 9;
  const float* Tp = T + (a * 64 + c) * 64;
  const float* h0 = h + (size_t)(a * 64 + c) * 4096;
  const float* h63 = h0 + 63 * 64;
  float acc = 0.f;
#pragma unroll
  for (int j = 0; j < 3; ++j) {
    int xi = x + j - 1;
    if (xi >= 0 && xi < 64) {
      float t = Tp[xi];
      float S0 = t - h63[xi];
      float S2 = t - h0[xi];
      acc = fmaf(dwp[j], S0, acc);
      acc = fmaf(dwp[3 + j], t, acc);
      acc = fmaf(dwp[6 + j], S2, acc);
    }
  }
  xd[idx] = acc;
}

__global__ __launch_bounds__(256) void outpre_kernel(
    const float* __restrict__ xd, const float* __restrict__ w4,
    const float* __restrict__ b4, float* __restrict__ out) {
  int idx = blockIdx.x * 256 + threadIdx.x;
  int x = idx & 63;
  int c = (idx >> 6) & 63;
  int o = (idx >> 12) & 63;
  int a = idx >> 18;
  const float* xp = xd + (size_t)(a * 4 * 64 + c) * 64 + x;
  float s = b4[o];
#pragma unroll
  for (int bb = 0; bb < 4; ++bb) s = fmaf(xp[bb * 4096], w4[o * 4 + bb], s);
  out[idx] = s;
}

__global__ __launch_bounds__(256) void bnstats_kernel(
    const float* __restrict__ out, float* __restrict__ stats) {
  int o = blockIdx.x;
  int tid = threadIdx.x;
  float s = 0.f, sq = 0.f;
  for (int i = tid; i < 4 * 64 * 64; i += 256) {
    int a = i >> 12;
    int rem = i & 4095;
    float v = out[(size_t)a * 262144 + o * 4096 + rem];
    s += v;
    sq = fmaf(v, v, sq);
  }
  __shared__ float ls[256], lq[256];
  ls[tid] = s; lq[tid] = sq;
  __syncthreads();
  for (int off = 128; off > 0; off >>= 1) {
    if (tid < off) { ls[tid] += ls[tid + off]; lq[tid] += lq[tid + off]; }
    __syncthreads();
  }
  if (tid == 0) {
    float mean = ls[0] * (1.f / 16384.f);
    float var = lq[0] * (1.f / 16384.f) - mean * mean;
    stats[o * 2] = mean;
    stats[o * 2 + 1] = rsqrtf(var + 1e-5f);
  }
}

__global__ __launch_bounds__(256) void bnapply_kernel(
    float* __restrict__ out, const float* __restrict__ stats,
    const float* __restrict__ gamma, const float* __restrict__ beta) {
  int idx = blockIdx.x * 256 + threadIdx.x;
  int o = (idx >> 12) & 63;
  float mean = stats[o * 2], rstd = stats[o * 2 + 1];
  out[idx] = (out[idx] - mean) * rstd * gamma[o] + beta[o];
}

// ---------------------------------------------------------------------------
extern "C" void kernel_launch(void* const* d_in, const int* in_sizes, int n_in,
                              void* d_out, int out_size, void* d_ws,
                              size_t ws_size, hipStream_t stream) {
  const float* x     = (const float*)d_in[0];
  const float* w1    = (const float*)d_in[1];
  const float* b1    = (const float*)d_in[2];
  const float* w2    = (const float*)d_in[3];
  const float* b2    = (const float*)d_in[4];
  const float* w3    = (const float*)d_in[5];
  const float* b3    = (const float*)d_in[6];
  const float* wd    = (const float*)d_in[7];
  const float* bd    = (const float*)d_in[8];
  const float* w4    = (const float*)d_in[9];
  const float* b4    = (const float*)d_in[10];
  const float* gamma = (const float*)d_in[11];
  const float* beta  = (const float*)d_in[12];
  float* out = (float*)d_out;

  // workspace carve (ushort offsets); h2n overlaps dead xn_pad to stay <48 MB
  ushort* us = (ushort*)d_ws;
  ushort* h1n_pad = us;                       // 4,460,544 (+32K read slack)
  ushort* xn_pad  = us + 4493312;             // 1,115,136 (+32K read slack)
  ushort* h2n     = us + 4493312;             // 16,777,216 (reuses xn region)
  ushort* w1p     = us + 21270528;            // 147,456
  ushort* w2p     = us + 21417984;            // 2,359,296
  ushort* w3p     = us + 23777280;            // 65,536
  float* fbase    = (float*)(us + 23842816);
  float* Tb     = fbase;                      // 16384
  float* pooled = Tb + 16384;                 // 256
  float* xdb    = pooled + 256;               // 65536
  float* stats  = xdb + 65536;                // 128
  float* hb     = out;                        // conv3 NCHW f32 lives in d_out

  pack_all<<<2648, 256, 0, stream>>>(x, w1, w2, w3, xn_pad, w1p, w2p, w3p,
                                     h1n_pad);

  hipFuncSetAttribute(reinterpret_cast<const void*>(conv_gemm2<1, 256, true>),
                      hipFuncAttributeMaxDynamicSharedMemorySize, 106496);
  hipFuncSetAttribute(reinterpret_cast<const void*>(conv_gemm2<4, 1024, false>),
                      hipFuncAttributeMaxDynamicSharedMemorySize, 106496);

  conv_gemm2<1, 256, true>
      <<<dim3(64, 2), 512, 106496, stream>>>(xn_pad, w1p, b1, h1n_pad);
  conv_gemm2<4, 1024, false>
      <<<dim3(64, 8), 512, 106496, stream>>>(h1n_pad, w2p, b2, h2n);
  conv_gemm_s<16, 1, 64, 2, 2, false, true>
      <<<dim3(256, 1), 256, 0, stream>>>(h2n, w3p, b3, nullptr, hb);

  colsum_pool<<<256, 64, 0, stream>>>(hb, Tb, pooled);
  xd_kernel<<<256, 256, 0, stream>>>(hb, Tb, pooled, wd, bd, xdb);
  outpre_kernel<<<4096, 256, 0, stream>>>(xdb, w4, b4, out);
  bnstats_kernel<<<64, 256, 0, stream>>>(out, stats);
  bnapply_kernel<<<4096, 256, 0, stream>>>(out, stats, gamma, beta);
}